// Round 8
// baseline (4638.824 us; speedup 1.0000x reference)
//
#include <hip/hip_runtime.h>
#include <cstdint>
#include <cstddef>

#define TLEN 512
#define BATCH 1000
#define NEVS 102400   // events per source
#define HID 64

__device__ __forceinline__ float fast_rcp(float x) {
#if __has_builtin(__builtin_amdgcn_rcpf)
    return __builtin_amdgcn_rcpf(x);
#else
    return 1.0f / x;
#endif
}
__device__ __forceinline__ float sigm(float x) { return fast_rcp(1.0f + __expf(-x)); }
__device__ __forceinline__ float tanh_f(float x) { return fmaf(2.0f, sigm(2.0f * x), -1.0f); }

// Wave-wide sum broadcast (rocPRIM gfx9 DPP pattern).
__device__ __forceinline__ float wave_sum_bcast(float x) {
#if __has_builtin(__builtin_amdgcn_update_dpp) && __has_builtin(__builtin_amdgcn_readlane)
    x += __int_as_float(__builtin_amdgcn_update_dpp(0, __float_as_int(x), 0x111, 0xf, 0xf, true)); // row_shr:1
    x += __int_as_float(__builtin_amdgcn_update_dpp(0, __float_as_int(x), 0x112, 0xf, 0xf, true)); // row_shr:2
    x += __int_as_float(__builtin_amdgcn_update_dpp(0, __float_as_int(x), 0x114, 0xf, 0xf, true)); // row_shr:4
    x += __int_as_float(__builtin_amdgcn_update_dpp(0, __float_as_int(x), 0x118, 0xf, 0xf, true)); // row_shr:8
    x += __int_as_float(__builtin_amdgcn_update_dpp(0, __float_as_int(x), 0x142, 0xa, 0xf, true)); // row_bcast:15
    x += __int_as_float(__builtin_amdgcn_update_dpp(0, __float_as_int(x), 0x143, 0xc, 0xf, true)); // row_bcast:31
    return __int_as_float(__builtin_amdgcn_readlane(__float_as_int(x), 63));
#else
#pragma unroll
    for (int off = 1; off < 64; off <<= 1) x += __shfl_xor(x, off, 64);
    return x;
#endif
}

// Two independent wave sums, stages interleaved for ILP.
__device__ __forceinline__ void wave_sum2(float& a, float& b) {
#if __has_builtin(__builtin_amdgcn_update_dpp) && __has_builtin(__builtin_amdgcn_readlane)
    int ta, tb;
    ta = __builtin_amdgcn_update_dpp(0, __float_as_int(a), 0x111, 0xf, 0xf, true);
    tb = __builtin_amdgcn_update_dpp(0, __float_as_int(b), 0x111, 0xf, 0xf, true);
    a += __int_as_float(ta); b += __int_as_float(tb);
    ta = __builtin_amdgcn_update_dpp(0, __float_as_int(a), 0x112, 0xf, 0xf, true);
    tb = __builtin_amdgcn_update_dpp(0, __float_as_int(b), 0x112, 0xf, 0xf, true);
    a += __int_as_float(ta); b += __int_as_float(tb);
    ta = __builtin_amdgcn_update_dpp(0, __float_as_int(a), 0x114, 0xf, 0xf, true);
    tb = __builtin_amdgcn_update_dpp(0, __float_as_int(b), 0x114, 0xf, 0xf, true);
    a += __int_as_float(ta); b += __int_as_float(tb);
    ta = __builtin_amdgcn_update_dpp(0, __float_as_int(a), 0x118, 0xf, 0xf, true);
    tb = __builtin_amdgcn_update_dpp(0, __float_as_int(b), 0x118, 0xf, 0xf, true);
    a += __int_as_float(ta); b += __int_as_float(tb);
    ta = __builtin_amdgcn_update_dpp(0, __float_as_int(a), 0x142, 0xa, 0xf, true);
    tb = __builtin_amdgcn_update_dpp(0, __float_as_int(b), 0x142, 0xa, 0xf, true);
    a += __int_as_float(ta); b += __int_as_float(tb);
    ta = __builtin_amdgcn_update_dpp(0, __float_as_int(a), 0x143, 0xc, 0xf, true);
    tb = __builtin_amdgcn_update_dpp(0, __float_as_int(b), 0x143, 0xc, 0xf, true);
    a += __int_as_float(ta); b += __int_as_float(tb);
    a = __int_as_float(__builtin_amdgcn_readlane(__float_as_int(a), 63));
    b = __int_as_float(__builtin_amdgcn_readlane(__float_as_int(b), 63));
#else
    a = wave_sum_bcast(a); b = wave_sum_bcast(b);
#endif
}

// ===========================================================================
// map[b*512+t] = src<<20 | e  (sources partition the (b,t) grid: exactly one)
// ===========================================================================
__global__ __launch_bounds__(256) void map_build_kernel(
    const int* __restrict__ b0, const int* __restrict__ t0,
    const int* __restrict__ b1, const int* __restrict__ t1,
    const int* __restrict__ b2, const int* __restrict__ t2,
    const int* __restrict__ b3, const int* __restrict__ t3,
    const int* __restrict__ b4, const int* __restrict__ t4,
    int* __restrict__ map)
{
    const int src = blockIdx.y;
    const int* bi = src == 0 ? b0 : src == 1 ? b1 : src == 2 ? b2 : src == 3 ? b3 : b4;
    const int* ti = src == 0 ? t0 : src == 1 ? t1 : src == 2 ? t2 : src == 3 ? t3 : t4;
    const int e = blockIdx.x * 256 + threadIdx.x;
    map[bi[e] * TLEN + ti[e]] = (src << 20) | e;
}

// ===========================================================================
// Composed projection weights: wp[row][col], row=(src,j) [130], col=dir*256+r.
// row j<IND: W_src[j] . Wih0[col]; row j==IND: b_src . Wih0[col] + bih+bhh.
// ===========================================================================
__global__ __launch_bounds__(512) void compose_kernel(
    const float* __restrict__ W0, const float* __restrict__ B0,
    const float* __restrict__ W1, const float* __restrict__ B1,
    const float* __restrict__ W2, const float* __restrict__ B2,
    const float* __restrict__ W3, const float* __restrict__ B3,
    const float* __restrict__ W4, const float* __restrict__ B4,
    const float* __restrict__ Wih, const float* __restrict__ bih,
    const float* __restrict__ bhh, float* __restrict__ wp)
{
    const int col = threadIdx.x;   // 0..511 == dir*256 + r == Wih row index
    const int row = blockIdx.x;    // 0..129
    const float* srcW; const float* srcB; int base, IND;
    if (row < 9)        { srcW = W0; srcB = B0; base = 0;   IND = 8;  }
    else if (row < 27)  { srcW = W1; srcB = B1; base = 9;   IND = 17; }
    else if (row < 53)  { srcW = W2; srcB = B2; base = 27;  IND = 25; }
    else if (row < 120) { srcW = W3; srcB = B3; base = 53;  IND = 66; }
    else                { srcW = W4; srcB = B4; base = 120; IND = 9;  }
    const int j = row - base;
    const float* xrow = (j < IND) ? (srcW + (size_t)j * 64) : srcB;
    const float* wr = Wih + (size_t)col * 64;
    float acc = 0.0f;
#pragma unroll
    for (int h2 = 0; h2 < 64; ++h2) acc = fmaf(xrow[h2], wr[h2], acc);
    if (j == IND) acc += bih[col] + bhh[col];
    wp[(size_t)row * 512 + col] = acc;
}

// ===========================================================================
// run_group: 4 events register-blocked against 4 weight rows per iteration.
// Wave-wide: lane = col-quad (256 cols of this dir). w reads are contiguous
// 1KB-row b128 (BW-saturating, conflict-free); x reads are uniform broadcast.
// Zero-padded rows/x make unaligned source boundaries read neighbors * 0.
// ===========================================================================
template<int NB, int BASE>
__device__ __forceinline__ void run_group(
    const float* __restrict__ wT, const float (*xb)[68],
    const int li[4], const bool val[4], const int pv[4],
    float* __restrict__ gdst, int lane)
{
    float acc[4][4] = {{0.f, 0.f, 0.f, 0.f}, {0.f, 0.f, 0.f, 0.f},
                       {0.f, 0.f, 0.f, 0.f}, {0.f, 0.f, 0.f, 0.f}};
#pragma unroll
    for (int jb = 0; jb < NB; ++jb) {
        float4 xk[4];
#pragma unroll
        for (int k = 0; k < 4; ++k) xk[k] = *(const float4*)&xb[li[k]][4 * jb];
        const float* w = wT + (size_t)(BASE + 4 * jb) * 256 + 4 * lane;
        const float4 w0 = *(const float4*)(w);
        const float4 w1 = *(const float4*)(w + 256);
        const float4 w2 = *(const float4*)(w + 512);
        const float4 w3 = *(const float4*)(w + 768);
#pragma unroll
        for (int k = 0; k < 4; ++k) {
            acc[k][0] = fmaf(xk[k].x, w0.x, acc[k][0]);
            acc[k][1] = fmaf(xk[k].x, w0.y, acc[k][1]);
            acc[k][2] = fmaf(xk[k].x, w0.z, acc[k][2]);
            acc[k][3] = fmaf(xk[k].x, w0.w, acc[k][3]);
            acc[k][0] = fmaf(xk[k].y, w1.x, acc[k][0]);
            acc[k][1] = fmaf(xk[k].y, w1.y, acc[k][1]);
            acc[k][2] = fmaf(xk[k].y, w1.z, acc[k][2]);
            acc[k][3] = fmaf(xk[k].y, w1.w, acc[k][3]);
            acc[k][0] = fmaf(xk[k].z, w2.x, acc[k][0]);
            acc[k][1] = fmaf(xk[k].z, w2.y, acc[k][1]);
            acc[k][2] = fmaf(xk[k].z, w2.z, acc[k][2]);
            acc[k][3] = fmaf(xk[k].z, w2.w, acc[k][3]);
            acc[k][0] = fmaf(xk[k].w, w3.x, acc[k][0]);
            acc[k][1] = fmaf(xk[k].w, w3.y, acc[k][1]);
            acc[k][2] = fmaf(xk[k].w, w3.z, acc[k][2]);
            acc[k][3] = fmaf(xk[k].w, w3.w, acc[k][3]);
        }
    }
#pragma unroll
    for (int k = 0; k < 4; ++k)
        if (val[k])
            *(float4*)(gdst + (size_t)pv[k] * 256 + 4 * lane) =
                make_float4(acc[k][0], acc[k][1], acc[k][2], acc[k][3]);
}

// ===========================================================================
// Projection, chunked: persistent blocks (1/CU, 512 thr) walk 64-position
// tiles of (b, lt) in order. Per tile: classify via map -> 8-wide parallel
// gather into LDS -> per-source 4-event register-blocked GEMM vs LDS W' ->
// contiguous row writes into the L3-resident chunk buffer.
// ===========================================================================
__global__ __launch_bounds__(512, 1) void project_kernel(
    const float* __restrict__ ccba_num,
    const float* __restrict__ cdtx_num, const int* __restrict__ cdtx_cat, const float* __restrict__ cdtx_tab,
    const float* __restrict__ cust_num, const int* __restrict__ cust_cat, const float* __restrict__ cust_tab,
    const float* __restrict__ dp_num,   const int* __restrict__ dp_cat,   const float* __restrict__ dp_tab,
    const float* __restrict__ remit_num, const int* __restrict__ remit_cat, const float* __restrict__ remit_tab,
    const float* __restrict__ wp, const int* __restrict__ map,
    float* __restrict__ gf, float* __restrict__ gb,
    int f0, int len, int tcm)
{
    __shared__ float wT[132 * 256];        // 135.2 KB: [row][col-of-dir]
    __shared__ float xbuf[64][68];         // 17.4 KB padded event inputs
    __shared__ int ev_e[64], ev_src[64], ev_pos[64];
    __shared__ int lists[5][64];
    __shared__ int cnt[5];
    __shared__ int glist[96];
    __shared__ int ng;

    const int tid = threadIdx.x;
    const int dir = blockIdx.y;
    const int lane = tid & 63, wave = tid >> 6;
    float* gdst = dir ? gb : gf;

    // Stage this dir's 256-col half of W' (+2 zero rows for padding).
    {
        const float4* wp4 = (const float4*)wp;   // 130 rows x 128 float4
        float4* wT4 = (float4*)wT;
        for (int i = tid; i < 132 * 64; i += 512) {
            const int row = i >> 6, c4 = i & 63;
            wT4[i] = (row < 130) ? wp4[(row << 7) + (dir << 6) + c4]
                                 : make_float4(0.f, 0.f, 0.f, 0.f);
        }
    }
    __syncthreads();

    const int npos = 1000 * len;
    const int ntiles = (npos + 63) >> 6;

    for (int tile = blockIdx.x; tile < ntiles; tile += gridDim.x) {
        if (tid < 5) cnt[tid] = 0;
        __syncthreads();

        // ---- classify 64 positions ----
        if (tid < 64) {
            const int idx = (tile << 6) + tid;
            int srcv = 0;
            if (idx < npos) {
                const int b = idx / len, lt = idx - b * len;
                const int t = dir ? (TLEN - 1 - f0 - lt) : (f0 + lt);
                const int mc = map[b * TLEN + t];
                srcv = mc >> 20;
                ev_e[tid] = mc & 0xFFFFF;
                ev_pos[tid] = b * tcm + lt;
                const int slot = atomicAdd(&cnt[srcv], 1);
                lists[srcv][slot] = tid;
            } else {
                ev_e[tid] = 0;
            }
            ev_src[tid] = srcv;
        }
        __syncthreads();

        if (tid == 0) {
            int g = 0;
            for (int s = 0; s < 5; ++s)
                for (int base = 0; base < cnt[s]; base += 4)
                    glist[g++] = (s << 8) | base;
            ng = g;
        }
        // ---- gather: 8 events in flight (wave = event) ----
        for (int r = 0; r < 64; r += 8) {
            const int i = r + wave;
            const int e = ev_e[i];
            const int s = ev_src[i];
            const int v = lane;
            float v0;
            switch (s) {
            case 0:
                v0 = (v < 8) ? ccba_num[(size_t)e * 8 + v] : (v == 8 ? 1.f : 0.f);
                if (v < 12) xbuf[i][v] = v0;
                break;
            case 1:
                v0 = (v < 16) ? cdtx_tab[(size_t)cdtx_cat[e * 2 + (v >> 3)] * 8 + (v & 7)]
                   : (v == 16 ? cdtx_num[e] : (v == 17 ? 1.f : 0.f));
                if (v < 20) xbuf[i][v] = v0;
                break;
            case 2:
                v0 = (v < 24) ? cust_tab[(size_t)cust_cat[e * 3 + (v >> 3)] * 8 + (v & 7)]
                   : (v == 24 ? cust_num[e] : (v == 25 ? 1.f : 0.f));
                if (v < 28) xbuf[i][v] = v0;
                break;
            case 3:
                xbuf[i][v] = dp_tab[(size_t)dp_cat[e * 8 + (v >> 3)] * 8 + (v & 7)];
                if (v < 4) xbuf[i][64 + v] = (v < 2) ? dp_num[(size_t)e * 2 + v]
                                                     : (v == 2 ? 1.f : 0.f);
                break;
            default:
                v0 = (v < 8) ? remit_tab[(size_t)remit_cat[e] * 8 + v]
                   : (v == 8 ? remit_num[e] : (v == 9 ? 1.f : 0.f));
                if (v < 12) xbuf[i][v] = v0;
                break;
            }
        }
        __syncthreads();

        // ---- compute: waves pull 4-event groups from the group list ----
        for (int gi = wave; gi < ng; gi += 8) {
            const int s = glist[gi] >> 8, base = glist[gi] & 255;
            const int n = cnt[s];
            int li[4]; bool val[4]; int pv[4];
#pragma unroll
            for (int k = 0; k < 4; ++k) {
                const int j = base + k;
                val[k] = j < n;
                li[k] = lists[s][val[k] ? j : base];
                pv[k] = ev_pos[li[k]];
            }
            switch (s) {
            case 0:  run_group<3, 0>(wT, xbuf, li, val, pv, gdst, lane);   break;
            case 1:  run_group<5, 9>(wT, xbuf, li, val, pv, gdst, lane);   break;
            case 2:  run_group<7, 27>(wT, xbuf, li, val, pv, gdst, lane);  break;
            case 3:  run_group<17, 53>(wT, xbuf, li, val, pv, gdst, lane); break;
            default: run_group<3, 120>(wT, xbuf, li, val, pv, gdst, lane); break;
            }
        }
        __syncthreads();   // protect xbuf/lists before next tile
    }
}

// ===========================================================================
// Layer-0 recurrence over the precomputed chunk (round-2 proven kernel):
// one wave per (b,dir); 2000 concurrent chains; 2-step gate prefetch;
// (h,c) carried across chunk launches.
// ===========================================================================
__global__ __launch_bounds__(256) void rec_chunk_kernel(
    const float* __restrict__ gf, const float* __restrict__ gb,
    const float* __restrict__ Whh, const float* __restrict__ Whr,
    float* __restrict__ h0, float* __restrict__ hs, float* __restrict__ cs,
    int f0, int len, int tcm, int first)
{
    const int wv = threadIdx.x >> 6, lane = threadIdx.x & 63;
    const int p = blockIdx.x * 4 + wv;          // 0..1999
    const int b = p >> 1, dir = p & 1;

    float whh4[4];
#pragma unroll
    for (int k = 0; k < 4; ++k) whh4[k] = Whh[dir * 256 + k * 64 + lane];
    const float whr = Whr[dir * HID + lane];

    const float* g = (dir ? gb : gf) + (size_t)b * tcm * 256 + lane;
    float* h0p = h0 + (size_t)b * TLEN * 2 + dir;

    float h, c;
    if (first) { h = 0.0f; c = 0.0f; }
    else       { h = hs[p]; c = cs[(size_t)p * 64 + lane]; }

    auto ga = [&](int s) -> const float* {
        const int sc = (s < len) ? s : (len - 1);   // clamp; value unused past end
        return g + (size_t)sc * 256;
    };
    auto do_step = [&](const float (&G)[4], int s) {
        const float gi = fmaf(whh4[0], h, G[0]);
        const float gfv = fmaf(whh4[1], h, G[1]);
        const float gg = fmaf(whh4[2], h, G[2]);
        const float go = fmaf(whh4[3], h, G[3]);
        c = sigm(gfv) * c + sigm(gi) * tanh_f(gg);
        h = wave_sum_bcast(sigm(go) * tanh_f(c) * whr);
        const int t_out = dir ? (TLEN - 1 - f0 - s) : (f0 + s);
        if (lane == 0) h0p[(size_t)t_out * 2] = h;
    };

    float A[4], B[4];
    {
        const float* pa = ga(0); const float* pb = ga(1);
#pragma unroll
        for (int k = 0; k < 4; ++k) { A[k] = pa[k * 64]; B[k] = pb[k * 64]; }
    }
    for (int s = 0; s < len; s += 2) {
        float C[4], D[4];
        const float* pc = ga(s + 2); const float* pd = ga(s + 3);
#pragma unroll
        for (int k = 0; k < 4; ++k) { C[k] = pc[k * 64]; D[k] = pd[k * 64]; }
        do_step(A, s);
        if (s + 1 < len) do_step(B, s + 1);
#pragma unroll
        for (int k = 0; k < 4; ++k) { A[k] = C[k]; B[k] = D[k]; }
    }
    if (lane == 0) hs[p] = h;
    cs[(size_t)p * 64 + lane] = c;
}

// ===========================================================================
// LSTM layer 1 (insz=2): one wave per b, BOTH dirs as two interleaved chains.
// ===========================================================================
__global__ __launch_bounds__(256, 2) void lstm1_kernel(
    const float* __restrict__ h0, const float* __restrict__ Wih,
    const float* __restrict__ Whh, const float* __restrict__ Whr,
    const float* __restrict__ bih, const float* __restrict__ bhh,
    float* __restrict__ h1)
{
    const int w = threadIdx.x >> 6, lane = threadIdx.x & 63;
    const int b = blockIdx.x * 4 + w;              // grid 250 -> b 0..999

    const volatile float* vWih = Wih;
    const volatile float* vWhh = Whh;
    const volatile float* vWhr = Whr;
    const volatile float* vbih = bih;
    const volatile float* vbhh = bhh;

    float wi0[2][4], wi1[2][4], whh[2][4], bias[2][4], whr[2];
#pragma unroll
    for (int d = 0; d < 2; ++d) {
#pragma unroll
        for (int k = 0; k < 4; ++k) {
            const int r = d * 256 + k * 64 + lane;
            wi0[d][k] = vWih[(size_t)r * 2 + 0];
            wi1[d][k] = vWih[(size_t)r * 2 + 1];
            whh[d][k] = vWhh[r];
            bias[d][k] = vbih[r] + vbhh[r];
        }
        whr[d] = vWhr[d * HID + lane];
    }
    float hA = 0, cA = 0, hB = 0, cB = 0;
    const float* hb = h0 + (size_t)b * TLEN * 2;

    float2 xA = *(const float2*)(hb);                          // fwd t=0
    float2 xB = *(const float2*)(hb + (size_t)(TLEN - 1) * 2); // bwd t=511
    for (int t = 0; t < TLEN; ++t) {
        const int tn = (t + 1 < TLEN) ? t + 1 : t;
        const float2 xAn = *(const float2*)(hb + (size_t)tn * 2);
        const float2 xBn = *(const float2*)(hb + (size_t)(TLEN - 1 - tn) * 2);
        float gA[4], gB[4];
#pragma unroll
        for (int k = 0; k < 4; ++k) {
            gA[k] = fmaf(whh[0][k], hA, fmaf(wi1[0][k], xA.y, fmaf(wi0[0][k], xA.x, bias[0][k])));
            gB[k] = fmaf(whh[1][k], hB, fmaf(wi1[1][k], xB.y, fmaf(wi0[1][k], xB.x, bias[1][k])));
        }
        cA = sigm(gA[1]) * cA + sigm(gA[0]) * tanh_f(gA[2]);
        cB = sigm(gB[1]) * cB + sigm(gB[0]) * tanh_f(gB[2]);
        float pA = sigm(gA[3]) * tanh_f(cA) * whr[0];
        float pB = sigm(gB[3]) * tanh_f(cB) * whr[1];
        wave_sum2(pA, pB);
        hA = pA; hB = pB;
        if (lane == 0) {
            h1[((size_t)b * TLEN + t) * 2 + 0] = hA;
            h1[((size_t)b * TLEN + (TLEN - 1 - t)) * 2 + 1] = hB;
        }
        xA = xAn; xB = xBn;
    }
}

__global__ __launch_bounds__(256) void mean_kernel(
    const float2* __restrict__ h1, float* __restrict__ out)
{
    int i = blockIdx.x * 256 + threadIdx.x;
    if (i < BATCH * TLEN) {
        float2 v = h1[i];
        out[i] = 0.5f * (v.x + v.y);
    }
}

// ===========================================================================
extern "C" void kernel_launch(void* const* d_in, const int* in_sizes, int n_in,
                              void* d_out, int out_size, void* d_ws, size_t ws_size,
                              hipStream_t stream)
{
    const float* ccba_num = (const float*)d_in[0];
    const int*   ccba_bi  = (const int*)d_in[1];
    const int*   ccba_ti  = (const int*)d_in[2];
    const float* ccba_W   = (const float*)d_in[3];
    const float* ccba_b   = (const float*)d_in[4];
    const float* cdtx_num = (const float*)d_in[5];
    const int*   cdtx_cat = (const int*)d_in[6];
    const float* cdtx_tab = (const float*)d_in[7];
    const int*   cdtx_bi  = (const int*)d_in[8];
    const int*   cdtx_ti  = (const int*)d_in[9];
    const float* cdtx_W   = (const float*)d_in[10];
    const float* cdtx_b   = (const float*)d_in[11];
    const float* cust_num = (const float*)d_in[12];
    const int*   cust_cat = (const int*)d_in[13];
    const float* cust_tab = (const float*)d_in[14];
    const int*   cust_bi  = (const int*)d_in[15];
    const int*   cust_ti  = (const int*)d_in[16];
    const float* cust_W   = (const float*)d_in[17];
    const float* cust_b   = (const float*)d_in[18];
    const float* dp_num   = (const float*)d_in[19];
    const int*   dp_cat   = (const int*)d_in[20];
    const float* dp_tab   = (const float*)d_in[21];
    const int*   dp_bi    = (const int*)d_in[22];
    const int*   dp_ti    = (const int*)d_in[23];
    const float* dp_W     = (const float*)d_in[24];
    const float* dp_b     = (const float*)d_in[25];
    const float* remit_num = (const float*)d_in[26];
    const int*   remit_cat = (const int*)d_in[27];
    const float* remit_tab = (const float*)d_in[28];
    const int*   remit_bi  = (const int*)d_in[29];
    const int*   remit_ti  = (const int*)d_in[30];
    const float* remit_W   = (const float*)d_in[31];
    const float* remit_b   = (const float*)d_in[32];
    const float* Wih0 = (const float*)d_in[33];
    const float* Whh0 = (const float*)d_in[34];
    const float* Whr0 = (const float*)d_in[35];
    const float* bih0 = (const float*)d_in[36];
    const float* bhh0 = (const float*)d_in[37];
    const float* Wih1 = (const float*)d_in[38];
    const float* Whh1 = (const float*)d_in[39];
    const float* Whr1 = (const float*)d_in[40];
    const float* bih1 = (const float*)d_in[41];
    const float* bhh1 = (const float*)d_in[42];

    float* out = (float*)d_out;

    // Workspace layout:
    //   gf, gb : 1000 * tcm * 256 * 4 each (chunk gate pre-activations, L3-fit)
    //   map    : 2,048,000
    //   h0, h1 : 4,096,000 each
    //   wp     : 266,240
    //   hs     : 8,000        cs : 512,000
    const size_t FIXED = 2048000ull + 4096000ull + 4096000ull + 266240ull
                       + 8000ull + 512000ull;
    size_t avail = (ws_size > FIXED) ? (ws_size - FIXED) : 0;
    int tcm = (int)(avail / 2048000ull);
    if (tcm < 1) tcm = 1;
    if (tcm > 86) tcm = 86;          // gf+gb <= 176 MB -> L3-resident
    if (tcm >= 2) tcm &= ~1;

    char* ws = (char*)d_ws;
    const size_t gfB = (size_t)tcm * 1024000ull;
    float* gf    = (float*)ws;
    float* gb    = (float*)(ws + gfB);
    char*  fixed = ws + 2 * gfB;
    int*   map   = (int*)  fixed;
    float* h0    = (float*)(fixed + 2048000ull);
    float* h1    = (float*)(fixed + 2048000ull + 4096000ull);
    float* wp    = (float*)(fixed + 2048000ull + 8192000ull);
    float* hs    = (float*)(fixed + 2048000ull + 8192000ull + 266240ull);
    float* cs    = (float*)(fixed + 2048000ull + 8192000ull + 266240ull + 8000ull);

    compose_kernel<<<130, 512, 0, stream>>>(
        ccba_W, ccba_b, cdtx_W, cdtx_b, cust_W, cust_b,
        dp_W, dp_b, remit_W, remit_b, Wih0, bih0, bhh0, wp);

    map_build_kernel<<<dim3(NEVS / 256, 5), 256, 0, stream>>>(
        ccba_bi, ccba_ti, cdtx_bi, cdtx_ti, cust_bi, cust_ti,
        dp_bi, dp_ti, remit_bi, remit_ti, map);

    int first = 1;
    for (int f0 = 0; f0 < TLEN; f0 += tcm) {
        const int len = (TLEN - f0 < tcm) ? (TLEN - f0) : tcm;
        project_kernel<<<dim3(128, 2), 512, 0, stream>>>(
            ccba_num,
            cdtx_num, cdtx_cat, cdtx_tab,
            cust_num, cust_cat, cust_tab,
            dp_num, dp_cat, dp_tab,
            remit_num, remit_cat, remit_tab,
            wp, map, gf, gb, f0, len, tcm);
        rec_chunk_kernel<<<500, 256, 0, stream>>>(
            gf, gb, Whh0, Whr0, h0, hs, cs, f0, len, tcm, first);
        first = 0;
    }

    lstm1_kernel<<<250, 256, 0, stream>>>(h0, Wih1, Whh1, Whr1, bih1, bhh1, h1);
    mean_kernel<<<(BATCH * TLEN + 255) / 256, 256, 0, stream>>>((const float2*)h1, out);
}

// Round 9
// 1520.968 us; speedup vs baseline: 3.0499x; 3.0499x over previous
//
#include <hip/hip_runtime.h>
#include <cstdint>
#include <cstddef>

#define TLEN 512
#define BATCH 1000
#define NEVS 102400   // events per source
#define HID 64

__device__ __forceinline__ float fast_rcp(float x) {
#if __has_builtin(__builtin_amdgcn_rcpf)
    return __builtin_amdgcn_rcpf(x);
#else
    return 1.0f / x;
#endif
}
__device__ __forceinline__ float sigm(float x) { return fast_rcp(1.0f + __expf(-x)); }
__device__ __forceinline__ float tanh_f(float x) { return fmaf(2.0f, sigm(2.0f * x), -1.0f); }

// Wave-wide sum broadcast (rocPRIM gfx9 DPP pattern).
__device__ __forceinline__ float wave_sum_bcast(float x) {
#if __has_builtin(__builtin_amdgcn_update_dpp) && __has_builtin(__builtin_amdgcn_readlane)
    x += __int_as_float(__builtin_amdgcn_update_dpp(0, __float_as_int(x), 0x111, 0xf, 0xf, true)); // row_shr:1
    x += __int_as_float(__builtin_amdgcn_update_dpp(0, __float_as_int(x), 0x112, 0xf, 0xf, true)); // row_shr:2
    x += __int_as_float(__builtin_amdgcn_update_dpp(0, __float_as_int(x), 0x114, 0xf, 0xf, true)); // row_shr:4
    x += __int_as_float(__builtin_amdgcn_update_dpp(0, __float_as_int(x), 0x118, 0xf, 0xf, true)); // row_shr:8
    x += __int_as_float(__builtin_amdgcn_update_dpp(0, __float_as_int(x), 0x142, 0xa, 0xf, true)); // row_bcast:15
    x += __int_as_float(__builtin_amdgcn_update_dpp(0, __float_as_int(x), 0x143, 0xc, 0xf, true)); // row_bcast:31
    return __int_as_float(__builtin_amdgcn_readlane(__float_as_int(x), 63));
#else
#pragma unroll
    for (int off = 1; off < 64; off <<= 1) x += __shfl_xor(x, off, 64);
    return x;
#endif
}

// Two independent wave sums, stages interleaved for ILP.
__device__ __forceinline__ void wave_sum2(float& a, float& b) {
#if __has_builtin(__builtin_amdgcn_update_dpp) && __has_builtin(__builtin_amdgcn_readlane)
    int ta, tb;
    ta = __builtin_amdgcn_update_dpp(0, __float_as_int(a), 0x111, 0xf, 0xf, true);
    tb = __builtin_amdgcn_update_dpp(0, __float_as_int(b), 0x111, 0xf, 0xf, true);
    a += __int_as_float(ta); b += __int_as_float(tb);
    ta = __builtin_amdgcn_update_dpp(0, __float_as_int(a), 0x112, 0xf, 0xf, true);
    tb = __builtin_amdgcn_update_dpp(0, __float_as_int(b), 0x112, 0xf, 0xf, true);
    a += __int_as_float(ta); b += __int_as_float(tb);
    ta = __builtin_amdgcn_update_dpp(0, __float_as_int(a), 0x114, 0xf, 0xf, true);
    tb = __builtin_amdgcn_update_dpp(0, __float_as_int(b), 0x114, 0xf, 0xf, true);
    a += __int_as_float(ta); b += __int_as_float(tb);
    ta = __builtin_amdgcn_update_dpp(0, __float_as_int(a), 0x118, 0xf, 0xf, true);
    tb = __builtin_amdgcn_update_dpp(0, __float_as_int(b), 0x118, 0xf, 0xf, true);
    a += __int_as_float(ta); b += __int_as_float(tb);
    ta = __builtin_amdgcn_update_dpp(0, __float_as_int(a), 0x142, 0xa, 0xf, true);
    tb = __builtin_amdgcn_update_dpp(0, __float_as_int(b), 0x142, 0xa, 0xf, true);
    a += __int_as_float(ta); b += __int_as_float(tb);
    ta = __builtin_amdgcn_update_dpp(0, __float_as_int(a), 0x143, 0xc, 0xf, true);
    tb = __builtin_amdgcn_update_dpp(0, __float_as_int(b), 0x143, 0xc, 0xf, true);
    a += __int_as_float(ta); b += __int_as_float(tb);
    a = __int_as_float(__builtin_amdgcn_readlane(__float_as_int(a), 63));
    b = __int_as_float(__builtin_amdgcn_readlane(__float_as_int(b), 63));
#else
    a = wave_sum_bcast(a); b = wave_sum_bcast(b);
#endif
}

// ===========================================================================
// map[b*512+t] = src<<20 | e  (sources partition the (b,t) grid: exactly one)
// ===========================================================================
__global__ __launch_bounds__(256) void map_build_kernel(
    const int* __restrict__ b0, const int* __restrict__ t0,
    const int* __restrict__ b1, const int* __restrict__ t1,
    const int* __restrict__ b2, const int* __restrict__ t2,
    const int* __restrict__ b3, const int* __restrict__ t3,
    const int* __restrict__ b4, const int* __restrict__ t4,
    int* __restrict__ map)
{
    const int src = blockIdx.y;
    const int* bi = src == 0 ? b0 : src == 1 ? b1 : src == 2 ? b2 : src == 3 ? b3 : b4;
    const int* ti = src == 0 ? t0 : src == 1 ? t1 : src == 2 ? t2 : src == 3 ? t3 : t4;
    const int e = blockIdx.x * 256 + threadIdx.x;
    map[bi[e] * TLEN + ti[e]] = (src << 20) | e;
}

// ===========================================================================
// Composed projection weights: wp[row][col], row=(src,j) [130], col=dir*256+r.
// row j<IND: W_src[j] . Wih0[col]; row j==IND: b_src . Wih0[col] + bih+bhh.
// ===========================================================================
__global__ __launch_bounds__(512) void compose_kernel(
    const float* __restrict__ W0, const float* __restrict__ B0,
    const float* __restrict__ W1, const float* __restrict__ B1,
    const float* __restrict__ W2, const float* __restrict__ B2,
    const float* __restrict__ W3, const float* __restrict__ B3,
    const float* __restrict__ W4, const float* __restrict__ B4,
    const float* __restrict__ Wih, const float* __restrict__ bih,
    const float* __restrict__ bhh, float* __restrict__ wp)
{
    const int col = threadIdx.x;   // 0..511 == dir*256 + r == Wih row index
    const int row = blockIdx.x;    // 0..129
    const float* srcW; const float* srcB; int base, IND;
    if (row < 9)        { srcW = W0; srcB = B0; base = 0;   IND = 8;  }
    else if (row < 27)  { srcW = W1; srcB = B1; base = 9;   IND = 17; }
    else if (row < 53)  { srcW = W2; srcB = B2; base = 27;  IND = 25; }
    else if (row < 120) { srcW = W3; srcB = B3; base = 53;  IND = 66; }
    else                { srcW = W4; srcB = B4; base = 120; IND = 9;  }
    const int j = row - base;
    const float* xrow = (j < IND) ? (srcW + (size_t)j * 64) : srcB;
    const float* wr = Wih + (size_t)col * 64;
    float acc = 0.0f;
#pragma unroll
    for (int h2 = 0; h2 < 64; ++h2) acc = fmaf(xrow[h2], wr[h2], acc);
    if (j == IND) acc += bih[col] + bhh[col];
    wp[(size_t)row * 512 + col] = acc;
}

__device__ __forceinline__ void fma4(float4& a, float x, const float4 w) {
    a.x = fmaf(x, w.x, a.x); a.y = fmaf(x, w.y, a.y);
    a.z = fmaf(x, w.z, a.z); a.w = fmaf(x, w.w, a.w);
}

// Pair-dot: 2 events of the SAME source share every weight read.
// Wave-wide: lane = col-quad. Per 4-row group: 4 w-b128 + 2 x-b128 + 32 FMA.
template<int NG, int BASE>
__device__ __forceinline__ void dot_pair(
    const float* __restrict__ wT, const float* __restrict__ xb0,
    const float* __restrict__ xb1, float4& a0, float4& a1, int lane)
{
#pragma unroll
    for (int g = 0; g < NG; ++g) {
        const float4 x0 = *(const float4*)(xb0 + 4 * g);
        const float4 x1 = *(const float4*)(xb1 + 4 * g);
        const float* w = wT + (size_t)(BASE + 4 * g) * 256 + 4 * lane;
        const float4 w0 = *(const float4*)(w);
        const float4 w1 = *(const float4*)(w + 256);
        const float4 w2 = *(const float4*)(w + 512);
        const float4 w3 = *(const float4*)(w + 768);
        fma4(a0, x0.x, w0); fma4(a0, x0.y, w1); fma4(a0, x0.z, w2); fma4(a0, x0.w, w3);
        fma4(a1, x1.x, w0); fma4(a1, x1.y, w1); fma4(a1, x1.z, w2); fma4(a1, x1.w, w3);
    }
}

// ===========================================================================
// Fused layer-0, v6: 8 SEQUENCES per block -> 250 blocks = ONE round on 256
// CUs (r7's killer was 7.8 serial rounds of a single chain). 1024 thr =
// 16 waves: waves 0-7 = consumers (one LSTM chain each, parallel SIMDs),
// waves 8-15 = gatherers; ALL 16 waves produce gates (same-source event
// pairs share weight reads -> LDS weight traffic halved). W' in LDS (r7-
// proven). Phase = 2 steps: [dot -> bar -> consume || gather -> bar].
// LDS: wT 135.2K + winP 16K + xsh 9.2K + srcs = 160.9 KB.
// ===========================================================================
__global__ __launch_bounds__(1024, 1) void fused0_kernel(
    const float* __restrict__ ccba_num,
    const float* __restrict__ cdtx_num, const int* __restrict__ cdtx_cat, const float* __restrict__ cdtx_tab,
    const float* __restrict__ cust_num, const int* __restrict__ cust_cat, const float* __restrict__ cust_tab,
    const float* __restrict__ dp_num,   const int* __restrict__ dp_cat,   const float* __restrict__ dp_tab,
    const float* __restrict__ remit_num, const int* __restrict__ remit_cat, const float* __restrict__ remit_tab,
    const float* __restrict__ wp, const int* __restrict__ map,
    const float* __restrict__ Whh, const float* __restrict__ Whr,
    float* __restrict__ h0)
{
    __shared__ float wT[132 * 256];      // [row][col-of-dir]; rows 130,131 = 0
    __shared__ float winP[8][2][256];    // gates for (b_local, step-in-phase)
    __shared__ float xsh[2][16][72];     // padded event inputs (bias folded)
    __shared__ int   srcs[2][16];

    const int tid = threadIdx.x;
    const int wave = tid >> 6, lane = tid & 63;
    const int dir = blockIdx.y;
    const int b0g = blockIdx.x * 8;

    // ---- stage W' (this dir's 256-col half; 2 zero pad rows) ----
    {
        const float4* wp4 = (const float4*)wp;   // 130 rows x 128 float4
        float4* wT4 = (float4*)wT;
        for (int i = tid; i < 132 * 64; i += 1024) {
            const int row = i >> 6, c4 = i & 63;
            wT4[i] = (row < 130) ? wp4[(row << 7) + (dir << 6) + c4]
                                 : make_float4(0.f, 0.f, 0.f, 0.f);
        }
    }

    // ---- consumer state (waves 0-7; b = b0g + wave) ----
    float whh4[4] = {0.f, 0.f, 0.f, 0.f};
    float whr = 0.f, h = 0.f, c = 0.f;
    float* h0p = nullptr;
    if (wave < 8) {
#pragma unroll
        for (int k = 0; k < 4; ++k) whh4[k] = Whh[dir * 256 + k * 64 + lane];
        whr = Whr[dir * HID + lane];
        h0p = h0 + (size_t)(b0g + wave) * TLEN * 2 + dir;
    }

    // gather events for phase pp into xsh[pp&1] (waves 8-15, 2 events each).
    auto gather = [&](int pp) {
        const int nbuf = pp & 1;
        const int gi = wave - 8;
#pragma unroll
        for (int q = 0; q < 2; ++q) {
            const int ev = gi * 2 + q;
            const int bl = ev >> 1, sl = ev & 1;
            const int s = 2 * pp + sl;
            const int t = dir ? (TLEN - 1 - s) : s;
            const int mc = map[(b0g + bl) * TLEN + t];
            const int src = mc >> 20, e = mc & 0xFFFFF;
            const int v = lane;
            if (v == 0) srcs[nbuf][ev] = src;
            float* xb = xsh[nbuf][ev];
            switch (src) {
            case 0:
                if (v < 12) xb[v] = (v < 8) ? ccba_num[(size_t)e * 8 + v]
                                            : (v == 8 ? 1.f : 0.f);
                break;
            case 1:
                if (v < 20) xb[v] = (v < 16) ? cdtx_tab[(size_t)cdtx_cat[e * 2 + (v >> 3)] * 8 + (v & 7)]
                                  : (v == 16 ? cdtx_num[e] : (v == 17 ? 1.f : 0.f));
                break;
            case 2:
                if (v < 28) xb[v] = (v < 24) ? cust_tab[(size_t)cust_cat[e * 3 + (v >> 3)] * 8 + (v & 7)]
                                  : (v == 24 ? cust_num[e] : (v == 25 ? 1.f : 0.f));
                break;
            case 3:
                xb[v] = dp_tab[(size_t)dp_cat[e * 8 + (v >> 3)] * 8 + (v & 7)];
                if (v < 4) xb[64 + v] = (v < 2) ? dp_num[(size_t)e * 2 + v]
                                                : (v == 2 ? 1.f : 0.f);
                break;
            default:
                if (v < 12) xb[v] = (v < 8) ? remit_tab[(size_t)remit_cat[e] * 8 + v]
                                  : (v == 8 ? remit_num[e] : (v == 9 ? 1.f : 0.f));
                break;
            }
        }
    };

    // ---- prologue: gather phase 0 ----
    if (wave >= 8) gather(0);
    __syncthreads();

    const int NPH = TLEN / 2;
    for (int p = 0; p < NPH; ++p) {
        const int buf = p & 1;

        // ---- dot: every wave derives its same-source event pair ----
        {
            unsigned m0 = 0, m1 = 0, m2 = 0, m3 = 0, m4 = 0;
#pragma unroll
            for (int ev = 0; ev < 16; ++ev) {
                const int s = srcs[buf][ev];
                const unsigned bit = 1u << ev;
                m0 |= (s == 0) ? bit : 0u;
                m1 |= (s == 1) ? bit : 0u;
                m2 |= (s == 2) ? bit : 0u;
                m3 |= (s == 3) ? bit : 0u;
                m4 |= (s == 4) ? bit : 0u;
            }
            int rem = wave, src = -1, ev0 = 0, ev1 = 0, pair = 0;
#pragma unroll
            for (int s = 0; s < 5; ++s) {
                const unsigned m = (s == 0) ? m0 : (s == 1) ? m1 : (s == 2) ? m2
                                 : (s == 3) ? m3 : m4;
                const int gs = (__popc(m) + 1) >> 1;
                if (src < 0) {
                    if (rem < gs) {
                        unsigned mm = m;
                        for (int k = 0; k < rem; ++k) { mm &= mm - 1; mm &= mm - 1; }
                        ev0 = __ffs(mm) - 1; mm &= mm - 1;
                        pair = (mm != 0);
                        ev1 = pair ? (__ffs(mm) - 1) : ev0;
                        src = s;
                    } else {
                        rem -= gs;
                    }
                }
            }
            if (src >= 0) {
                const float* xb0 = xsh[buf][ev0];
                const float* xb1 = xsh[buf][ev1];
                float4 a0 = make_float4(0.f, 0.f, 0.f, 0.f);
                float4 a1 = make_float4(0.f, 0.f, 0.f, 0.f);
                switch (src) {
                case 0:  dot_pair<3, 0>(wT, xb0, xb1, a0, a1, lane);   break;
                case 1:  dot_pair<5, 9>(wT, xb0, xb1, a0, a1, lane);   break;
                case 2:  dot_pair<7, 27>(wT, xb0, xb1, a0, a1, lane);  break;
                case 3:  dot_pair<17, 53>(wT, xb0, xb1, a0, a1, lane); break;
                default: dot_pair<3, 120>(wT, xb0, xb1, a0, a1, lane); break;
                }
                ((float4*)&winP[ev0 >> 1][ev0 & 1][0])[lane] = a0;
                if (pair) ((float4*)&winP[ev1 >> 1][ev1 & 1][0])[lane] = a1;
            }
        }
        __syncthreads();

        // ---- consume (waves 0-7) || gather next phase (waves 8-15) ----
        if (wave < 8) {
            float G0[4], G1[4];
#pragma unroll
            for (int k = 0; k < 4; ++k) {
                G0[k] = winP[wave][0][k * 64 + lane];
                G1[k] = winP[wave][1][k * 64 + lane];
            }
            {
                const float gi = fmaf(whh4[0], h, G0[0]);
                const float gf = fmaf(whh4[1], h, G0[1]);
                const float gg = fmaf(whh4[2], h, G0[2]);
                const float go = fmaf(whh4[3], h, G0[3]);
                c = sigm(gf) * c + sigm(gi) * tanh_f(gg);
                h = wave_sum_bcast(sigm(go) * tanh_f(c) * whr);
                const int s = 2 * p;
                const int t = dir ? (TLEN - 1 - s) : s;
                if (lane == 0) h0p[(size_t)t * 2] = h;
            }
            {
                const float gi = fmaf(whh4[0], h, G1[0]);
                const float gf = fmaf(whh4[1], h, G1[1]);
                const float gg = fmaf(whh4[2], h, G1[2]);
                const float go = fmaf(whh4[3], h, G1[3]);
                c = sigm(gf) * c + sigm(gi) * tanh_f(gg);
                h = wave_sum_bcast(sigm(go) * tanh_f(c) * whr);
                const int s = 2 * p + 1;
                const int t = dir ? (TLEN - 1 - s) : s;
                if (lane == 0) h0p[(size_t)t * 2] = h;
            }
        } else if (p + 1 < NPH) {
            gather(p + 1);
        }
        __syncthreads();
    }
}

// ===========================================================================
// LSTM layer 1 (insz=2): one wave per b, BOTH dirs as two interleaved chains.
// (unchanged from round 7 — passed)
// ===========================================================================
__global__ __launch_bounds__(256, 2) void lstm1_kernel(
    const float* __restrict__ h0, const float* __restrict__ Wih,
    const float* __restrict__ Whh, const float* __restrict__ Whr,
    const float* __restrict__ bih, const float* __restrict__ bhh,
    float* __restrict__ h1)
{
    const int w = threadIdx.x >> 6, lane = threadIdx.x & 63;
    const int b = blockIdx.x * 4 + w;              // grid 250 -> b 0..999

    const volatile float* vWih = Wih;
    const volatile float* vWhh = Whh;
    const volatile float* vWhr = Whr;
    const volatile float* vbih = bih;
    const volatile float* vbhh = bhh;

    float wi0[2][4], wi1[2][4], whh[2][4], bias[2][4], whr[2];
#pragma unroll
    for (int d = 0; d < 2; ++d) {
#pragma unroll
        for (int k = 0; k < 4; ++k) {
            const int r = d * 256 + k * 64 + lane;
            wi0[d][k] = vWih[(size_t)r * 2 + 0];
            wi1[d][k] = vWih[(size_t)r * 2 + 1];
            whh[d][k] = vWhh[r];
            bias[d][k] = vbih[r] + vbhh[r];
        }
        whr[d] = vWhr[d * HID + lane];
    }
    float hA = 0, cA = 0, hB = 0, cB = 0;
    const float* hb = h0 + (size_t)b * TLEN * 2;

    float2 xA = *(const float2*)(hb);                          // fwd t=0
    float2 xB = *(const float2*)(hb + (size_t)(TLEN - 1) * 2); // bwd t=511
    for (int t = 0; t < TLEN; ++t) {
        const int tn = (t + 1 < TLEN) ? t + 1 : t;
        const float2 xAn = *(const float2*)(hb + (size_t)tn * 2);
        const float2 xBn = *(const float2*)(hb + (size_t)(TLEN - 1 - tn) * 2);
        float gA[4], gB[4];
#pragma unroll
        for (int k = 0; k < 4; ++k) {
            gA[k] = fmaf(whh[0][k], hA, fmaf(wi1[0][k], xA.y, fmaf(wi0[0][k], xA.x, bias[0][k])));
            gB[k] = fmaf(whh[1][k], hB, fmaf(wi1[1][k], xB.y, fmaf(wi0[1][k], xB.x, bias[1][k])));
        }
        cA = sigm(gA[1]) * cA + sigm(gA[0]) * tanh_f(gA[2]);
        cB = sigm(gB[1]) * cB + sigm(gB[0]) * tanh_f(gB[2]);
        float pA = sigm(gA[3]) * tanh_f(cA) * whr[0];
        float pB = sigm(gB[3]) * tanh_f(cB) * whr[1];
        wave_sum2(pA, pB);
        hA = pA; hB = pB;
        if (lane == 0) {
            h1[((size_t)b * TLEN + t) * 2 + 0] = hA;
            h1[((size_t)b * TLEN + (TLEN - 1 - t)) * 2 + 1] = hB;
        }
        xA = xAn; xB = xBn;
    }
}

__global__ __launch_bounds__(256) void mean_kernel(
    const float2* __restrict__ h1, float* __restrict__ out)
{
    int i = blockIdx.x * 256 + threadIdx.x;
    if (i < BATCH * TLEN) {
        float2 v = h1[i];
        out[i] = 0.5f * (v.x + v.y);
    }
}

// ===========================================================================
extern "C" void kernel_launch(void* const* d_in, const int* in_sizes, int n_in,
                              void* d_out, int out_size, void* d_ws, size_t ws_size,
                              hipStream_t stream)
{
    const float* ccba_num = (const float*)d_in[0];
    const int*   ccba_bi  = (const int*)d_in[1];
    const int*   ccba_ti  = (const int*)d_in[2];
    const float* ccba_W   = (const float*)d_in[3];
    const float* ccba_b   = (const float*)d_in[4];
    const float* cdtx_num = (const float*)d_in[5];
    const int*   cdtx_cat = (const int*)d_in[6];
    const float* cdtx_tab = (const float*)d_in[7];
    const int*   cdtx_bi  = (const int*)d_in[8];
    const int*   cdtx_ti  = (const int*)d_in[9];
    const float* cdtx_W   = (const float*)d_in[10];
    const float* cdtx_b   = (const float*)d_in[11];
    const float* cust_num = (const float*)d_in[12];
    const int*   cust_cat = (const int*)d_in[13];
    const float* cust_tab = (const float*)d_in[14];
    const int*   cust_bi  = (const int*)d_in[15];
    const int*   cust_ti  = (const int*)d_in[16];
    const float* cust_W   = (const float*)d_in[17];
    const float* cust_b   = (const float*)d_in[18];
    const float* dp_num   = (const float*)d_in[19];
    const int*   dp_cat   = (const int*)d_in[20];
    const float* dp_tab   = (const float*)d_in[21];
    const int*   dp_bi    = (const int*)d_in[22];
    const int*   dp_ti    = (const int*)d_in[23];
    const float* dp_W     = (const float*)d_in[24];
    const float* dp_b     = (const float*)d_in[25];
    const float* remit_num = (const float*)d_in[26];
    const int*   remit_cat = (const int*)d_in[27];
    const float* remit_tab = (const float*)d_in[28];
    const int*   remit_bi  = (const int*)d_in[29];
    const int*   remit_ti  = (const int*)d_in[30];
    const float* remit_W   = (const float*)d_in[31];
    const float* remit_b   = (const float*)d_in[32];
    const float* Wih0 = (const float*)d_in[33];
    const float* Whh0 = (const float*)d_in[34];
    const float* Whr0 = (const float*)d_in[35];
    const float* bih0 = (const float*)d_in[36];
    const float* bhh0 = (const float*)d_in[37];
    const float* Wih1 = (const float*)d_in[38];
    const float* Whh1 = (const float*)d_in[39];
    const float* Whr1 = (const float*)d_in[40];
    const float* bih1 = (const float*)d_in[41];
    const float* bhh1 = (const float*)d_in[42];

    float* out = (float*)d_out;

    // Workspace: wp (266,240) | map (2,048,000) | h0 (4,096,000) | h1 (4,096,000)
    char* ws = (char*)d_ws;
    float* wp  = (float*)ws;
    int*   map = (int*)  (ws + 266240ull);
    float* h0  = (float*)(ws + 266240ull + 2048000ull);
    float* h1  = (float*)(ws + 266240ull + 2048000ull + 4096000ull);

    compose_kernel<<<130, 512, 0, stream>>>(
        ccba_W, ccba_b, cdtx_W, cdtx_b, cust_W, cust_b,
        dp_W, dp_b, remit_W, remit_b, Wih0, bih0, bhh0, wp);

    map_build_kernel<<<dim3(NEVS / 256, 5), 256, 0, stream>>>(
        ccba_bi, ccba_ti, cdtx_bi, cdtx_ti, cust_bi, cust_ti,
        dp_bi, dp_ti, remit_bi, remit_ti, map);

    fused0_kernel<<<dim3(BATCH / 8, 2), 1024, 0, stream>>>(
        ccba_num,
        cdtx_num, cdtx_cat, cdtx_tab,
        cust_num, cust_cat, cust_tab,
        dp_num, dp_cat, dp_tab,
        remit_num, remit_cat, remit_tab,
        wp, map, Whh0, Whr0, h0);

    lstm1_kernel<<<250, 256, 0, stream>>>(h0, Wih1, Whh1, Whr1, bih1, bhh1, h1);
    mean_kernel<<<(BATCH * TLEN + 255) / 256, 256, 0, stream>>>((const float2*)h1, out);
}